// Round 9
// baseline (1384.398 us; speedup 1.0000x reference)
//
#include <hip/hip_runtime.h>

typedef __attribute__((ext_vector_type(4))) float f32x4;
typedef __attribute__((ext_vector_type(8))) short bf16x8;
typedef __attribute__((ext_vector_type(4))) unsigned int u32x4;

static __device__ __forceinline__ unsigned short f2bf(float f) {
  union { float f; unsigned int u; } v;
  v.f = f;
  unsigned int r = v.u + 0x7fffu + ((v.u >> 16) & 1u);  // RNE
  return (unsigned short)(r >> 16);
}
static __device__ __forceinline__ unsigned packbf(float a, float b) {
  return (unsigned)f2bf(a) | ((unsigned)f2bf(b) << 16);
}
static __device__ __forceinline__ void gload16(const void* g, void* l) {
  __builtin_amdgcn_global_load_lds(
      (const __attribute__((address_space(1))) unsigned int*)g,
      (__attribute__((address_space(3))) unsigned int*)l, 16, 0, 0);
}

// ---------------------------------------------------------------------------
// Pack:
//  - w2: LSQ fake-quant to bf16 frags (bf16(round(clip(w/a2))*a2)), 128 KB at
//    ws[0..131072): frag (cf*8+ks) at byte (cf*8+ks)*1024 + lane*16.
//  - w1: 4-bit codes (round(clip(w/a1)), alpha folded in epilogue), 32 KB at
//    ws[131072..163840): dword (cf*8+ks)*64 + lane.
// Frag content: lane l holds wq[n][k], n = cf*16+(l&15), k = ks*32+(l>>4)*8+j.
// ---------------------------------------------------------------------------
__global__ void lsq_pack(const float* __restrict__ w1, const float* __restrict__ a1,
                         const float* __restrict__ w2, const float* __restrict__ a2,
                         char* __restrict__ ws)
{
  int g = blockIdx.x * 256 + threadIdx.x;     // 0..16383
  int gg = g & 8191;
  int l  = gg & 63;
  int ks = (gg >> 6) & 7;
  int cf = gg >> 9;
  int n  = cf * 16 + (l & 15);
  int kb = ks * 32 + (l >> 4) * 8;
  if (g < 8192) {                              // w1 -> nibble codes
    float alpha = *a1;
    const float* src = w1 + n * 256 + kb;
    unsigned cw = 0;
    #pragma unroll
    for (int j = 0; j < 8; ++j) {
      float q = src[j] / alpha;
      q = fminf(fmaxf(q, -8.f), 7.f);
      int k = (int)rintf(q);                   // round-half-even == jnp.round
      cw |= ((unsigned)k & 0xFu) << (4 * j);
    }
    *(unsigned*)(ws + 131072 + gg * 4) = cw;
  } else {                                     // w2 -> bf16 frags
    float alpha = *a2;
    const float* src = w2 + n * 256 + kb;
    unsigned short e[8];
    #pragma unroll
    for (int j = 0; j < 8; ++j) {
      float q = src[j] / alpha;
      q = fminf(fmaxf(q, -8.f), 7.f);
      q = rintf(q) * alpha;
      e[j] = f2bf(q);
    }
    uint4 o;
    o.x = e[0] | ((unsigned)e[1] << 16);
    o.y = e[2] | ((unsigned)e[3] << 16);
    o.z = e[4] | ((unsigned)e[5] << 16);
    o.w = e[6] | ((unsigned)e[7] << 16);
    *(uint4*)(ws + gg * 16) = o;
  }
}

// Dequant one w1 frag: nibble codes -> bf16 integers (-8..7, exact).
static __device__ __forceinline__ bf16x8 deq(const char* cbase, int fr) {
  unsigned cw = *(const unsigned*)(cbase + (fr << 8));
  union { u32x4 u; bf16x8 v; } cv;
  #pragma unroll
  for (int p = 0; p < 4; ++p) {
    int k0 = ((int)(cw << (28 - 8 * p))) >> 28;
    int k1 = ((int)(cw << (24 - 8 * p))) >> 28;
    cv.u[p] = __builtin_amdgcn_perm(__float_as_uint((float)k1),
                                    __float_as_uint((float)k0), 0x07060302u);
  }
  return cv.v;
}

// ---------------------------------------------------------------------------
// Fused: out = sigmoid(relu(alpha1*(x@k1^T) + b1) @ wq2^T + b2)
// 512 thr (8 waves), wave-tile 16 rows, block-tile 128, 1 block/CU.
// LDS (160 KiB exactly): w2 bf16 frags (128K, layer-2 = ds_read+MFMA, no deq)
// + w1 codes (32K, layer-1 deq, alpha1 in epilogue). x fully register-
// prefetched (split halves under layer-1). Biases from global (L1-hot).
// ZERO barriers and ZERO explicit waitcnt after the prologue.
// ---------------------------------------------------------------------------
__global__ __launch_bounds__(512, 2) void lsq_fused(
    const float* __restrict__ x, const char* __restrict__ wsg,
    const float* __restrict__ b1, const float* __restrict__ b2,
    const float* __restrict__ a1p, float* __restrict__ out, int ntiles)
{
  __shared__ __align__(16) char lds[163840];

  const int tid  = threadIdx.x;
  const int lane = tid & 63;
  const int w    = tid >> 6;
  const int l15  = lane & 15;
  const int l4   = lane >> 4;
  const char* const cbase = lds + 131072 + (lane << 2);  // w1 codes base
  const int G = gridDim.x;
  const f32x4 fz = {0.f, 0.f, 0.f, 0.f};
  const float alpha1 = *a1p;

  // bpermute gather indices (R3..R8-verified transpose)
  int idx[4];
  #pragma unroll
  for (int wi = 0; wi < 4; ++wi)
    idx[wi] = (((l4 & 1) * 2 + (wi >> 1)) * 16 + l15) * 4;

  // ---- prologue: 160K weights -> LDS; first tile x -> regs ----
  #pragma unroll
  for (int it = 0; it < 20; ++it) {
    const int off = (it * 512 + tid) * 16;
    gload16(wsg + off, lds + off);
  }

  int t = blockIdx.x;
  f32x4 raw[16];
  {
    const float* xp = x + ((size_t)t * 128 + w * 16 + l15) * 256 + l4 * 8;
    #pragma unroll
    for (int ks = 0; ks < 8; ++ks) {
      raw[2 * ks]     = *(const f32x4*)(xp + ks * 32);
      raw[2 * ks + 1] = *(const f32x4*)(xp + ks * 32 + 4);
    }
  }
  __syncthreads();   // the ONLY barrier: weights visible

  for (;;) {
    // ---- convert x -> bf16 B-frags (frees raw) ----
    bf16x8 xf[8];
    #pragma unroll
    for (int ks = 0; ks < 8; ++ks) {
      bf16x8 b;
      #pragma unroll
      for (int j = 0; j < 4; ++j) {
        b[j]     = (short)f2bf(raw[2 * ks][j]);
        b[j + 4] = (short)f2bf(raw[2 * ks + 1][j]);
      }
      xf[ks] = b;
    }

    const int tn = t + G;
    const bool more = tn < ntiles;
    const float* xq = x + ((size_t)tn * 128 + w * 16 + l15) * 256 + l4 * 8;

    // ---- layer 1: deq(w1 codes) + MFMA; hf built in-register ----
    bf16x8 hf[8];
    #pragma unroll
    for (int p = 0; p < 8; ++p) {
      if (p == 2 && more) {                    // prefetch next-tile x, half 0
        #pragma unroll
        for (int ks = 0; ks < 4; ++ks) {
          raw[2 * ks]     = *(const f32x4*)(xq + ks * 32);
          raw[2 * ks + 1] = *(const f32x4*)(xq + ks * 32 + 4);
        }
      }
      if (p == 5 && more) {                    // half 1
        #pragma unroll
        for (int ks = 4; ks < 8; ++ks) {
          raw[2 * ks]     = *(const f32x4*)(xq + ks * 32);
          raw[2 * ks + 1] = *(const f32x4*)(xq + ks * 32 + 4);
        }
      }
      f32x4 a0 = fz, a1v = fz;
      #pragma unroll
      for (int ks = 0; ks < 8; ++ks) {
        a0  = __builtin_amdgcn_mfma_f32_16x16x32_bf16(deq(cbase, p * 16 + ks), xf[ks], a0, 0, 0, 0);
        a1v = __builtin_amdgcn_mfma_f32_16x16x32_bf16(deq(cbase, p * 16 + 8 + ks), xf[ks], a1v, 0, 0, 0);
      }
      f32x4 bv0 = *(const f32x4*)(b1 + p * 32 + l4 * 4);
      f32x4 bv1 = *(const f32x4*)(b1 + p * 32 + 16 + l4 * 4);
      f32x4 v0, v1;
      #pragma unroll
      for (int j = 0; j < 4; ++j) {
        v0[j] = fmaxf(fmaf(a0[j],  alpha1, bv0[j]), 0.f);
        v1[j] = fmaxf(fmaf(a1v[j], alpha1, bv1[j]), 0.f);
      }
      const unsigned D0 = packbf(v0[0], v0[1]);
      const unsigned D1 = packbf(v0[2], v0[3]);
      const unsigned D2 = packbf(v1[0], v1[1]);
      const unsigned D3 = packbf(v1[2], v1[3]);
      unsigned hd[4];
      #pragma unroll
      for (int wi = 0; wi < 4; ++wi) {
        const int p0 = __builtin_amdgcn_ds_bpermute(idx[wi], (int)((wi & 1) ? D1 : D0));
        const int p1 = __builtin_amdgcn_ds_bpermute(idx[wi], (int)((wi & 1) ? D3 : D2));
        hd[wi] = (l4 >= 2) ? (unsigned)p1 : (unsigned)p0;
      }
      union { u32x4 u; bf16x8 v; } cv;
      cv.u[0] = hd[0]; cv.u[1] = hd[1]; cv.u[2] = hd[2]; cv.u[3] = hd[3];
      hf[p] = cv.v;
    }

    // ---- layer 2: pure ds_read_b128 + MFMA (w2 pre-dequantized bf16) ----
    float* op = out + ((size_t)t * 128 + w * 16 + l15) * 256 + l4 * 4;
    #pragma unroll
    for (int q = 0; q < 8; ++q) {
      f32x4 g0 = fz, g1 = fz;
      #pragma unroll
      for (int ks2 = 0; ks2 < 8; ++ks2) {
        bf16x8 wf0 = *(const bf16x8*)(lds + ((2 * q)     * 8 + ks2) * 1024 + lane * 16);
        bf16x8 wf1 = *(const bf16x8*)(lds + ((2 * q + 1) * 8 + ks2) * 1024 + lane * 16);
        g0 = __builtin_amdgcn_mfma_f32_16x16x32_bf16(wf0, hf[ks2], g0, 0, 0, 0);
        g1 = __builtin_amdgcn_mfma_f32_16x16x32_bf16(wf1, hf[ks2], g1, 0, 0, 0);
      }
      f32x4 bb0 = *(const f32x4*)(b2 + q * 32 + l4 * 4);
      f32x4 bb1 = *(const f32x4*)(b2 + q * 32 + 16 + l4 * 4);
      f32x4 o0, o1;
      #pragma unroll
      for (int j = 0; j < 4; ++j) {
        const float z0 = g0[j] + bb0[j];
        const float z1 = g1[j] + bb1[j];
        o0[j] = 1.f / (1.f + __expf(-z0));
        o1[j] = 1.f / (1.f + __expf(-z1));
      }
      *(f32x4*)(op + (2 * q) * 16)     = o0;
      *(f32x4*)(op + (2 * q + 1) * 16) = o1;
    }

    if (!more) break;
    t = tn;
  }
}

// ---------------------------------------------------------------------------
extern "C" void kernel_launch(void* const* d_in, const int* in_sizes, int n_in,
                              void* d_out, int out_size, void* d_ws, size_t ws_size,
                              hipStream_t stream)
{
  const float* x  = (const float*)d_in[0];
  const float* w1 = (const float*)d_in[1];
  const float* b1 = (const float*)d_in[2];
  const float* a1 = (const float*)d_in[3];
  const float* w2 = (const float*)d_in[4];
  const float* b2 = (const float*)d_in[5];
  const float* a2 = (const float*)d_in[6];
  float* out = (float*)d_out;
  (void)ws_size;

  char* ws = (char*)d_ws;                       // 160 KB packed weights

  long long totalRows = (long long)in_sizes[0] / 256;
  int ntiles = (int)(totalRows / 128);          // 2048 at N=262144

  lsq_pack<<<64, 256, 0, stream>>>(w1, a1, w2, a2, ws);

  int grid = ntiles < 256 ? ntiles : 256;       // 1 block/CU
  lsq_fused<<<grid, 512, 0, stream>>>(x, ws, b1, b2, a1, out, ntiles);
}